// Round 2
// baseline (524.612 us; speedup 1.0000x reference)
//
#include <hip/hip_runtime.h>
#include <math.h>

#define ITERS 100
#define EPS 1e-12f

// Literal transcription of _squash: 0.02 + 0.96 * sigmoid(x), accurate expf,
// IEEE division.
__device__ __forceinline__ float squash(float x) {
    return 0.02f + 0.96f / (1.0f + expf(-x));
}

__global__ __launch_bounds__(256) void sinkhorn_km_kernel(
    const float* __restrict__ margins,
    const float* __restrict__ W1, const float* __restrict__ b1,
    const float* __restrict__ W2, const float* __restrict__ b2,
    const float* __restrict__ W3, const float* __restrict__ b3,
    const float* __restrict__ Wtau,
    float* __restrict__ out, int B)
{
    const int b = blockIdx.x * blockDim.x + threadIdx.x;
    if (b >= B) return;

    // ---- load 12 margins (coalesced float4; b*48 bytes is 16B aligned)
    const float4* mp = (const float4*)(margins + (size_t)b * 12);
    float4 m0 = mp[0], m1 = mp[1], m2 = mp[2];
    float mar[12] = {m0.x, m0.y, m0.z, m0.w,
                     m1.x, m1.y, m1.z, m1.w,
                     m2.x, m2.y, m2.z, m2.w};

    // ---- MLP: 12 -> 32 (relu) -> 16 (relu) -> 18
    float h1[32];
#pragma unroll
    for (int o = 0; o < 32; ++o) {
        float acc = b1[o];
#pragma unroll
        for (int i = 0; i < 12; ++i) acc = fmaf(mar[i], W1[i * 32 + o], acc);
        h1[o] = acc > 0.0f ? acc : 0.0f;
    }
    float h2[16];
#pragma unroll
    for (int o = 0; o < 16; ++o) {
        float acc = b2[o];
#pragma unroll
        for (int i = 0; i < 32; ++i) acc = fmaf(h1[i], W2[i * 16 + o], acc);
        h2[o] = acc > 0.0f ? acc : 0.0f;
    }
    float pars[18];
#pragma unroll
    for (int o = 0; o < 18; ++o) {
        float acc = b3[o];
#pragma unroll
        for (int i = 0; i < 16; ++i) acc = fmaf(h2[i], W3[i * 18 + o], acc);
        pars[o] = acc;
    }

    // ---- marginals
    // shm0 = [sq(p9), sq(p10), 1, sq(p11), sq(p12), 1]
    // shf0 = [sq(p13), sq(p14), 1, sq(p15), sq(p16), 1]
    float shm[6] = {squash(pars[9]),  squash(pars[10]), 1.0f,
                    squash(pars[11]), squash(pars[12]), 1.0f};
    float shf[6] = {squash(pars[13]), squash(pars[14]), 1.0f,
                    squash(pars[15]), squash(pars[16]), 1.0f};
    const float V = expf(pars[17]);

    float rm[6], cm[6], mum[6], muf[6];
#pragma unroll
    for (int j = 0; j < 6; ++j) {
        float Mj = mar[j], Fj = mar[6 + j];
        rm[j]  = Mj * shm[j];            // mucm0 -> row targets
        mum[j] = Mj * (1.0f - shm[j]);   // mum0
        cm[j]  = Fj * shf[j];            // muc0f -> col targets
        muf[j] = Fj * (1.0f - shf[j]);   // mu0f
    }

    // ---- A = exp(einsum('k,kij->ij', pars[0:8], Wtau)), kept as full matrix
    float A[36];
#pragma unroll
    for (int e = 0; e < 36; ++e) {
        float acc = 0.0f;
#pragma unroll
        for (int k = 0; k < 8; ++k) acc = fmaf(pars[k], Wtau[k * 36 + e], acc);
        A[e] = expf(acc);
    }

    // ---- Sinkhorn, literal matrix form with EPS exactly as in the reference
    for (int t = 0; t < ITERS; ++t) {
        // A = A * (rm / (A.sum(axis=1/rows... i.e. sum over j) + EPS))
#pragma unroll
        for (int i = 0; i < 6; ++i) {
            float s = 0.0f;
#pragma unroll
            for (int j = 0; j < 6; ++j) s += A[i * 6 + j];
            float f = rm[i] / (s + EPS);
#pragma unroll
            for (int j = 0; j < 6; ++j) A[i * 6 + j] *= f;
        }
        // A = A * (cm / (A.sum(over i) + EPS))
#pragma unroll
        for (int j = 0; j < 6; ++j) {
            float s = 0.0f;
#pragma unroll
            for (int i = 0; i < 6; ++i) s += A[i * 6 + j];
            float g = cm[j] / (s + EPS);
#pragma unroll
            for (int i = 0; i < 6; ++i) A[i * 6 + j] *= g;
        }
    }

    // ---- write mus (7x7 per row) and V
    float* o = out + (size_t)b * 49;
#pragma unroll
    for (int i = 0; i < 6; ++i) {
#pragma unroll
        for (int j = 0; j < 6; ++j) o[i * 7 + j] = A[i * 6 + j];
        o[i * 7 + 6] = mum[i];
    }
#pragma unroll
    for (int j = 0; j < 6; ++j) o[42 + j] = muf[j];
    o[48] = 0.0f;
    out[(size_t)B * 49 + b] = V;
}

extern "C" void kernel_launch(void* const* d_in, const int* in_sizes, int n_in,
                              void* d_out, int out_size, void* d_ws, size_t ws_size,
                              hipStream_t stream) {
    const float* margins = (const float*)d_in[0];
    const float* W1   = (const float*)d_in[1];
    const float* b1   = (const float*)d_in[2];
    const float* W2   = (const float*)d_in[3];
    const float* b2   = (const float*)d_in[4];
    const float* W3   = (const float*)d_in[5];
    const float* b3   = (const float*)d_in[6];
    const float* Wtau = (const float*)d_in[7];
    const int B = in_sizes[0] / 12;

    dim3 block(256);
    dim3 grid((B + 255) / 256);
    hipLaunchKernelGGL(sinkhorn_km_kernel, grid, block, 0, stream,
                       margins, W1, b1, W2, b2, W3, b3, Wtau,
                       (float*)d_out, B);
}

// Round 3
// 358.379 us; speedup vs baseline: 1.4638x; 1.4638x over previous
//
#include <hip/hip_runtime.h>
#include <math.h>

#define ITERS 100
#define EPS 1e-12f

// v_rcp_f32: <=1 ulp relative error. Error headroom is ~5x (absmax 3.9e-3 vs
// threshold 2.08e-2 with IEEE div), so 1-ulp reciprocals are safe.
__device__ __forceinline__ float fast_rcp(float x) {
    return __builtin_amdgcn_rcpf(x);
}

// Literal _squash: 0.02 + 0.96 * sigmoid(x), accurate expf + IEEE div
// (one-time cost, ~5 calls/thread -- not worth touching).
__device__ __forceinline__ float squash(float x) {
    return 0.02f + 0.96f / (1.0f + expf(-x));
}

// block=256, min 4 waves/EU: VGPR budget 128 (live set ~50-60 floats in the
// Sinkhorn loop; the default 64-VGPR cap caused scratch spills in R2).
__global__ __launch_bounds__(256, 4) void sinkhorn_km_kernel(
    const float* __restrict__ margins,
    const float* __restrict__ W1, const float* __restrict__ b1,
    const float* __restrict__ W2, const float* __restrict__ b2,
    const float* __restrict__ W3, const float* __restrict__ b3,
    const float* __restrict__ Wtau,
    float* __restrict__ out, int B)
{
    const int b = blockIdx.x * blockDim.x + threadIdx.x;
    if (b >= B) return;

    // ---- load 12 margins (coalesced float4; b*48 bytes is 16B aligned)
    const float4* mp = (const float4*)(margins + (size_t)b * 12);
    float4 m0 = mp[0], m1 = mp[1], m2 = mp[2];
    float mar[12] = {m0.x, m0.y, m0.z, m0.w,
                     m1.x, m1.y, m1.z, m1.w,
                     m2.x, m2.y, m2.z, m2.w};

    // ---- MLP: 12 -> 32 (relu) -> 16 (relu) -> 18  (weights wave-uniform ->
    //      compiler emits s_load; SGPR operand feeds v_fma directly)
    float h1[32];
#pragma unroll
    for (int o = 0; o < 32; ++o) {
        float acc = b1[o];
#pragma unroll
        for (int i = 0; i < 12; ++i) acc = fmaf(mar[i], W1[i * 32 + o], acc);
        h1[o] = acc > 0.0f ? acc : 0.0f;
    }
    float h2[16];
#pragma unroll
    for (int o = 0; o < 16; ++o) {
        float acc = b2[o];
#pragma unroll
        for (int i = 0; i < 32; ++i) acc = fmaf(h1[i], W2[i * 16 + o], acc);
        h2[o] = acc > 0.0f ? acc : 0.0f;
    }
    float pars[18];
#pragma unroll
    for (int o = 0; o < 18; ++o) {
        float acc = b3[o];
#pragma unroll
        for (int i = 0; i < 16; ++i) acc = fmaf(h2[i], W3[i * 18 + o], acc);
        pars[o] = acc;
    }

    // ---- marginals
    float shm[6] = {squash(pars[9]),  squash(pars[10]), 1.0f,
                    squash(pars[11]), squash(pars[12]), 1.0f};
    float shf[6] = {squash(pars[13]), squash(pars[14]), 1.0f,
                    squash(pars[15]), squash(pars[16]), 1.0f};
    const float V = expf(pars[17]);

    float rm[6], cm[6];
    float* o = out + (size_t)b * 49;
#pragma unroll
    for (int j = 0; j < 6; ++j) {
        float Mj = mar[j], Fj = mar[6 + j];
        rm[j] = Mj * shm[j];                  // mucm0 -> row targets
        cm[j] = Fj * shf[j];                  // muc0f -> col targets
        // write mum0 / mu0f now: frees their registers before the hot loop
        o[j * 7 + 6] = Mj * (1.0f - shm[j]);  // mum0 -> col 6, rows 0..5
        o[42 + j]    = Fj * (1.0f - shf[j]);  // mu0f -> row 6, cols 0..5
    }
    o[48] = 0.0f;
    out[(size_t)B * 49 + b] = V;

    // ---- A = exp(einsum('k,kij->ij', pars[0:8], Wtau))
    float A[36];
#pragma unroll
    for (int e = 0; e < 36; ++e) {
        float acc = 0.0f;
#pragma unroll
        for (int k = 0; k < 8; ++k) acc = fmaf(pars[k], Wtau[k * 36 + e], acc);
        A[e] = expf(acc);
    }

    // ---- Sinkhorn, literal matrix form (known-good structure from R2);
    //      only the divides are replaced by rcp-multiplies.
    for (int t = 0; t < ITERS; ++t) {
#pragma unroll
        for (int i = 0; i < 6; ++i) {
            float s = 0.0f;
#pragma unroll
            for (int j = 0; j < 6; ++j) s += A[i * 6 + j];
            float f = rm[i] * fast_rcp(s + EPS);
#pragma unroll
            for (int j = 0; j < 6; ++j) A[i * 6 + j] *= f;
        }
#pragma unroll
        for (int j = 0; j < 6; ++j) {
            float s = 0.0f;
#pragma unroll
            for (int i = 0; i < 6; ++i) s += A[i * 6 + j];
            float g = cm[j] * fast_rcp(s + EPS);
#pragma unroll
            for (int i = 0; i < 6; ++i) A[i * 6 + j] *= g;
        }
    }

    // ---- write the 6x6 block
#pragma unroll
    for (int i = 0; i < 6; ++i) {
#pragma unroll
        for (int j = 0; j < 6; ++j) o[i * 7 + j] = A[i * 6 + j];
    }
}

extern "C" void kernel_launch(void* const* d_in, const int* in_sizes, int n_in,
                              void* d_out, int out_size, void* d_ws, size_t ws_size,
                              hipStream_t stream) {
    const float* margins = (const float*)d_in[0];
    const float* W1   = (const float*)d_in[1];
    const float* b1   = (const float*)d_in[2];
    const float* W2   = (const float*)d_in[3];
    const float* b2   = (const float*)d_in[4];
    const float* W3   = (const float*)d_in[5];
    const float* b3   = (const float*)d_in[6];
    const float* Wtau = (const float*)d_in[7];
    const int B = in_sizes[0] / 12;

    dim3 block(256);
    dim3 grid((B + 255) / 256);
    hipLaunchKernelGGL(sinkhorn_km_kernel, grid, block, 0, stream,
                       margins, W1, b1, W2, b2, W3, b3, Wtau,
                       (float*)d_out, B);
}

// Round 4
// 182.446 us; speedup vs baseline: 2.8754x; 1.9643x over previous
//
#include <hip/hip_runtime.h>
#include <math.h>

#define MAX_ITERS 100
#define EPS 1e-12f
#define TOL 3e-5f

// v_rcp_f32: <=1 ulp. Proven neutral on absmax in R3 (0.00390625 unchanged,
// which is the bf16 quantization floor -- we have ~100x numeric slack).
__device__ __forceinline__ float fast_rcp(float x) {
    return __builtin_amdgcn_rcpf(x);
}

// _squash = 0.02 + 0.96*sigmoid(x); native exp + rcp (error ~1e-7 rel,
// irrelevant vs the 3.9e-3 bf16 comparison floor).
__device__ __forceinline__ float squash(float x) {
    return 0.02f + 0.96f * fast_rcp(1.0f + __expf(-x));
}

// (256,2): register ceiling 256. R3's (256,4)=128 cap made the compiler park
// A[36] in AGPRs and shuttle via v_accvgpr_read/write every access (~2x VALU
// instruction overhead, VGPR_Count=44 with zero scratch traffic). Live set in
// the loop is ~55 floats -> fits cleanly now.
__global__ __launch_bounds__(256, 2) void sinkhorn_km_kernel(
    const float* __restrict__ margins,
    const float* __restrict__ W1, const float* __restrict__ b1,
    const float* __restrict__ W2, const float* __restrict__ b2,
    const float* __restrict__ W3, const float* __restrict__ b3,
    const float* __restrict__ Wtau,
    float* __restrict__ out, int B)
{
    // mum0[6], mu0f[6], V parked in LDS during the loop: avoids (a) 12 extra
    // live registers, (b) R3's double HBM write (early-written lines evicted
    // during the loop, re-dirtied by the final 6x6 stores -> WRITE_SIZE 2x).
    // Stride 13 (odd) -> lane l hits banks (13*l)%32, bijective, conflict-free.
    __shared__ float side[256 * 13];
    const int tid = threadIdx.x;
    const int b = blockIdx.x * 256 + tid;
    if (b >= B) return;
    float* sd = side + tid * 13;

    // ---- load 12 margins (coalesced float4; 48B/row, 16B aligned)
    const float4* mp = (const float4*)(margins + (size_t)b * 12);
    float4 m0 = mp[0], m1 = mp[1], m2 = mp[2];
    float mar[12] = {m0.x, m0.y, m0.z, m0.w,
                     m1.x, m1.y, m1.z, m1.w,
                     m2.x, m2.y, m2.z, m2.w};

    // ---- MLP: 12 -> 32 (relu) -> 16 (relu) -> 18; weights are wave-uniform
    //      (s_load into SGPRs, feed v_fma as the scalar operand)
    float h1[32];
#pragma unroll
    for (int o = 0; o < 32; ++o) {
        float acc = b1[o];
#pragma unroll
        for (int i = 0; i < 12; ++i) acc = fmaf(mar[i], W1[i * 32 + o], acc);
        h1[o] = acc > 0.0f ? acc : 0.0f;
    }
    float h2[16];
#pragma unroll
    for (int o = 0; o < 16; ++o) {
        float acc = b2[o];
#pragma unroll
        for (int i = 0; i < 32; ++i) acc = fmaf(h1[i], W2[i * 16 + o], acc);
        h2[o] = acc > 0.0f ? acc : 0.0f;
    }
    float pars[18];
#pragma unroll
    for (int o = 0; o < 18; ++o) {
        float acc = b3[o];
#pragma unroll
        for (int i = 0; i < 16; ++i) acc = fmaf(h2[i], W3[i * 18 + o], acc);
        pars[o] = acc;
    }

    // ---- marginals; mum/muf/V go straight to LDS
    float shm[6] = {squash(pars[9]),  squash(pars[10]), 1.0f,
                    squash(pars[11]), squash(pars[12]), 1.0f};
    float shf[6] = {squash(pars[13]), squash(pars[14]), 1.0f,
                    squash(pars[15]), squash(pars[16]), 1.0f};
    float rm[6], cm[6];
#pragma unroll
    for (int j = 0; j < 6; ++j) {
        float Mj = mar[j], Fj = mar[6 + j];
        rm[j] = Mj * shm[j];         // mucm0 (row targets)
        cm[j] = Fj * shf[j];         // muc0f (col targets)
        sd[j]     = Mj - rm[j];      // mum0 = M*(1-shm)
        sd[6 + j] = Fj - cm[j];      // mu0f = F*(1-shf)
    }
    sd[12] = __expf(pars[17]);       // V

    // ---- A = exp(einsum('k,kij->ij', pars[0:8], Wtau))
    float A[36];
#pragma unroll
    for (int e = 0; e < 36; ++e) {
        float acc = 0.0f;
#pragma unroll
        for (int k = 0; k < 8; ++k) acc = fmaf(pars[k], Wtau[k * 36 + e], acc);
        A[e] = __expf(acc);
    }

    // ---- Sinkhorn (matrix form, validated R2/R3) with early exit.
    // At the limit cycle the row factors f_i are lane-uniform; spread(f) < TOL
    // certifies remaining distance to the limit ~ TOL*c/(1-c) ~ 1e-4 rel,
    // far below the 3.9e-3 error floor. Break only when ALL 64 lanes converge
    // (wave-uniform branch). Cap = 100 = reference iteration count.
    for (int t = 0; t < MAX_ITERS; ++t) {
        float f[6];
#pragma unroll
        for (int i = 0; i < 6; ++i) {
            float s = 0.0f;
#pragma unroll
            for (int j = 0; j < 6; ++j) s += A[i * 6 + j];
            f[i] = rm[i] * fast_rcp(s + EPS);
#pragma unroll
            for (int j = 0; j < 6; ++j) A[i * 6 + j] *= f[i];
        }
#pragma unroll
        for (int j = 0; j < 6; ++j) {
            float s = 0.0f;
#pragma unroll
            for (int i = 0; i < 6; ++i) s += A[i * 6 + j];
            float g = cm[j] * fast_rcp(s + EPS);
#pragma unroll
            for (int i = 0; i < 6; ++i) A[i * 6 + j] *= g;
        }
        float fmax = fmaxf(fmaxf(fmaxf(f[0], f[1]), fmaxf(f[2], f[3])),
                           fmaxf(f[4], f[5]));
        float fmin = fminf(fminf(fminf(f[0], f[1]), fminf(f[2], f[3])),
                           fminf(f[4], f[5]));
        if (__all(fmax - fmin <= TOL * fmax)) break;
    }

    // ---- epilogue: all HBM writes happen here, once per line
    float* o = out + (size_t)b * 49;
#pragma unroll
    for (int i = 0; i < 6; ++i) {
#pragma unroll
        for (int j = 0; j < 6; ++j) o[i * 7 + j] = A[i * 6 + j];
        o[i * 7 + 6] = sd[i];
    }
#pragma unroll
    for (int j = 0; j < 6; ++j) o[42 + j] = sd[6 + j];
    o[48] = 0.0f;
    out[(size_t)B * 49 + b] = sd[12];
}

extern "C" void kernel_launch(void* const* d_in, const int* in_sizes, int n_in,
                              void* d_out, int out_size, void* d_ws, size_t ws_size,
                              hipStream_t stream) {
    const float* margins = (const float*)d_in[0];
    const float* W1   = (const float*)d_in[1];
    const float* b1   = (const float*)d_in[2];
    const float* W2   = (const float*)d_in[3];
    const float* b2   = (const float*)d_in[4];
    const float* W3   = (const float*)d_in[5];
    const float* b3   = (const float*)d_in[6];
    const float* Wtau = (const float*)d_in[7];
    const int B = in_sizes[0] / 12;

    dim3 block(256);
    dim3 grid((B + 255) / 256);
    hipLaunchKernelGGL(sinkhorn_km_kernel, grid, block, 0, stream,
                       margins, W1, b1, W2, b2, W3, b3, Wtau,
                       (float*)d_out, B);
}